// Round 1
// baseline (120.471 us; speedup 1.0000x reference)
//
#include <hip/hip_runtime.h>

// CapsuleConv2d: x (4,32,56,56) f32, weight (P_out=4,P_in=4,K=9,L_in=8,L_out=16) f32
// out (4, 64, 56, 56) f32.  3x3 conv, stride 1, pad 1, 3 routing iterations.
//
// Mapping: lane d = tid&15 (L_out), p = (tid>>4)&3 (P_in), si = tid>>6 (site in block).
// One wave = one (n,o,h,w) site with all 4 p planes; 16-lane shuffle groups do the
// d-reductions (squash norm, logits update); xor-16/32 shuffles do the final sum over p.

#define HW56 56
#define HW2 (56*56)

__global__ __launch_bounds__(256) void caps_routing_kernel(
    const float* __restrict__ x, const float* __restrict__ wgt,
    float* __restrict__ out)
{
    const int tid = threadIdx.x;
    const int d  = tid & 15;
    const int p  = (tid >> 4) & 3;
    const int si = tid >> 6;

    int site = blockIdx.x * 4 + si;            // over N*P_out*H*W = 50176
    const int w = site % HW56;
    int t = site / HW56;
    const int h = t % HW56;
    t /= HW56;
    const int o = t & 3;
    const int n = t >> 2;

    // ---- priors M[k] = sum_l patch[n,p,l,h,w,k] * weight[o,p,k,l,d] ----
    const float* wg = wgt + ((o * 4 + p) * 9) * 8 * 16 + d;   // + k*128 + l*16
    const float* xb = x + (n * 32 + p * 8) * HW2;             // + l*HW2 + hh*56 + ww

    float M[9];
    #pragma unroll
    for (int k = 0; k < 9; ++k) {
        const int hh = h + (k / 3) - 1;
        const int ww = w + (k % 3) - 1;
        float m = 0.f;
        if ((unsigned)hh < 56u && (unsigned)ww < 56u) {
            const float* xp = xb + hh * HW56 + ww;
            const float* wp = wg + k * 128;
            #pragma unroll
            for (int l = 0; l < 8; ++l)
                m = fmaf(xp[l * HW2], wp[l * 16], m);
        }
        M[k] = m;
    }

    // ---- dynamic routing (3 iters) ----
    float b[9];
    #pragma unroll
    for (int k = 0; k < 9; ++k) b[k] = 0.f;
    float v = 0.f;

    #pragma unroll
    for (int it = 0; it < 3; ++it) {
        // softmax over k (stable), then s_d = sum_k probs_k * M[k]
        float mx = b[0];
        #pragma unroll
        for (int k = 1; k < 9; ++k) mx = fmaxf(mx, b[k]);
        float se = 0.f, s = 0.f;
        #pragma unroll
        for (int k = 0; k < 9; ++k) {
            const float e = __expf(b[k] - mx);
            se += e;
            s = fmaf(e, M[k], s);
        }
        s /= se;

        // squash: |s|^2 over the 16 d-lanes
        float sq = s * s;
        sq += __shfl_xor(sq, 1, 64);
        sq += __shfl_xor(sq, 2, 64);
        sq += __shfl_xor(sq, 4, 64);
        sq += __shfl_xor(sq, 8, 64);
        v = s * sqrtf(sq) / (1.f + sq);   // (sq/(1+sq)) * s / sqrt(sq)

        if (it < 2) {
            // b_k += sum_d M[k][d] * v_d
            #pragma unroll
            for (int k = 0; k < 9; ++k) {
                float u = M[k] * v;
                u += __shfl_xor(u, 1, 64);
                u += __shfl_xor(u, 2, 64);
                u += __shfl_xor(u, 4, 64);
                u += __shfl_xor(u, 8, 64);
                b[k] += u;
            }
        }
    }

    // ---- sum over p (bits 4,5 of lane id) and store ----
    v += __shfl_xor(v, 16, 64);
    v += __shfl_xor(v, 32, 64);
    if (p == 0) {
        // out[n][o*16+d][h][w]
        out[((n * 64 + o * 16 + d) * HW56 + h) * HW56 + w] = v;
    }
}

extern "C" void kernel_launch(void* const* d_in, const int* in_sizes, int n_in,
                              void* d_out, int out_size, void* d_ws, size_t ws_size,
                              hipStream_t stream) {
    const float* x   = (const float*)d_in[0];
    const float* wgt = (const float*)d_in[1];
    float* out = (float*)d_out;

    // sites = N*P_out*H*W = 4*4*56*56 = 50176; 4 sites per 256-thread block
    const int grid = 50176 / 4;   // 12544
    caps_routing_kernel<<<dim3(grid), dim3(256), 0, stream>>>(x, wgt, out);
}